// Round 1
// baseline (359.655 us; speedup 1.0000x reference)
//
#include <hip/hip_runtime.h>

#define BB 256
#define NN 4096
#define CC 16
#define WW 10
#define LL 4087  // N - W + 1
#define EPSF 1e-5f

// ---------------- Kernel 0: pack + zero-pad weights into ws (512 KB) ----------------
// pk[n*16+c] = {Wr[c,n], Wi[c,n]}, zeros for n >= LL
__global__ __launch_bounds__(256) void pack_weights(const float* __restrict__ Wr,
                                                    const float* __restrict__ Wi,
                                                    float2* __restrict__ pk) {
    int tg = blockIdx.x * 256 + threadIdx.x;  // [0, 65536)
    int n = tg >> 4, c = tg & 15;
    float2 v = make_float2(0.f, 0.f);
    if (n < LL) { v.x = Wr[c * LL + n]; v.y = Wi[c * LL + n]; }
    pk[tg] = v;
}

// ---------------- Kernel 1: fused stage1+2+3, one block per b, 1024 threads ----------------
// 1024 threads = 64 tc (n-chunks of 64) x 16 c. Rolling 16-slot weight window,
// x read exactly once as float2. 16 waves/CU = 4 waves/SIMD for latency hiding.
// NOTE (R3): float4/lane + nontemporal loads regressed (−11.6 us); keep float2, no nt.
// NOTE (R5): fusing BN via last-block finalizer regressed (−9.4 us); keep separate bnorm.
// R6: fully unroll the g-loop (64 static steps; mod-16 window becomes pure renaming)
//     and batch each chunk's 16 x-loads into xb[] issued ahead of the FMA block, so
//     the compiler can overlap chunk g+1's HBM stream with chunk g's compute.
//     Theory: stage1 was latency-bound (~70us vs ~21us BW floor) due to the
//     unroll-1 back-edge limiting loads in flight.
template <bool PK>
__global__ __launch_bounds__(1024) void fused_main(const float* __restrict__ x,
                                                   const float2* __restrict__ pk,
                                                   const float* __restrict__ Wr,
                                                   const float* __restrict__ Wi,
                                                   const float* __restrict__ Wnl,
                                                   const float* __restrict__ Wor,
                                                   const float* __restrict__ Woi,
                                                   float* __restrict__ outraw) {
    const int b = blockIdx.x;
    const int tid = threadIdx.x;
    const int tc = tid >> 4;   // 0..63
    const int c = tid & 15;
    const int n0 = tc * 64;

    const float2* __restrict__ x2 = (const float2*)x + (size_t)b * (NN * CC) + (n0 * 16 + c);
    const float2* __restrict__ pkp = pk + (n0 * 16 + c);

    float wr[16], wi[16];
    float fr[WW], fi[WW];
#pragma unroll
    for (int w = 0; w < WW; ++w) { fr[w] = 0.f; fi[w] = 0.f; }

    // prefill slots 15..7 with weights n0-1..n0-9 (zero if negative)
#pragma unroll
    for (int i = 1; i <= 9; ++i) {
        const int m = n0 - i;
        float vr = 0.f, vi = 0.f;
        if (PK) {
            if (m >= 0) { const float2 t = pk[m * 16 + c]; vr = t.x; vi = t.y; }
        } else {
            const int mc = m < 0 ? 0 : m;
            const float a = Wr[c * LL + mc], q = Wi[c * LL + mc];
            vr = (m >= 0) ? a : 0.f;
            vi = (m >= 0) ? q : 0.f;
        }
        wr[16 - i] = vr;
        wi[16 - i] = vi;
    }

    // main loop: fully unrolled (4 chunks x 16 steps, all offsets static).
#pragma unroll
    for (int g = 0; g < 4; ++g) {
        // batch-issue this chunk's 16 x loads first (independent of the FMA block
        // below); with full unroll the scheduler can slide chunk g+1's loads
        // under chunk g's 320 FMAs.
        float2 xb[16];
#pragma unroll
        for (int p = 0; p < 16; ++p) xb[p] = x2[(g * 16 + p) * 16];

#pragma unroll
        for (int p = 0; p < 16; ++p) {
            const int n = n0 + g * 16 + p;
            float vr, vi;
            if (PK) {
                const float2 t = pkp[(g * 16 + p) * 16];
                vr = t.x; vi = t.y;
            } else {
                const int nc2 = (n < LL) ? n : (LL - 1);
                const float a = Wr[c * LL + nc2], q = Wi[c * LL + nc2];
                vr = (n < LL) ? a : 0.f;
                vi = (n < LL) ? q : 0.f;
            }
            wr[p & 15] = vr;
            wi[p & 15] = vi;
#pragma unroll
            for (int w = 0; w < WW; ++w) {
                fr[w] += xb[p].x * wr[(p - w) & 15];
                fi[w] += xb[p].y * wi[(p - w) & 15];
            }
        }
    }

    // reduce over tc: within a wave tc occupies lane bits 4..5 -> xor-reduce,
    // then 16 wave-partials via LDS.
#pragma unroll
    for (int w = 0; w < WW; ++w) {
        fr[w] += __shfl_xor(fr[w], 16);
        fr[w] += __shfl_xor(fr[w], 32);
        fi[w] += __shfl_xor(fi[w], 16);
        fi[w] += __shfl_xor(fi[w], 32);
    }
    __shared__ float red[16][320];
    __shared__ float F2[320];
    __shared__ float nls[320];
    const int lane = tid & 63, wave = tid >> 6;
    if (lane < 16) {  // lane == c for these lanes
#pragma unroll
        for (int w = 0; w < WW; ++w) {
            red[wave][lane * 20 + w] = fr[w];
            red[wave][lane * 20 + 10 + w] = fi[w];
        }
    }
    __syncthreads();
    if (tid < 320) {
        float s = 0.f;
#pragma unroll
        for (int k = 0; k < 16; ++k) s += red[k][tid];
        F2[tid] = s;  // slot = c*20 + j*10 + w  (j=0:real, 1:imag)
    }
    __syncthreads();
    // amplitude scaling
    if (tid < 160) {
        const int cc = tid / 10, w = tid % 10;
        const float a = F2[cc * 20 + w], q = F2[cc * 20 + 10 + w];
        const float amp = a * a + q * q;
        F2[cc * 20 + w] = a * amp;
        F2[cc * 20 + 10 + w] = q * amp;
    }
    __syncthreads();
    // nl[w,c,o] = sum_i tf[w,i] * Wnl[c,o,i]
    if (tid < 320) {
        const int cc = tid / 20, rem = tid % 20, o = rem / 10, w = rem % 10;
        const float* __restrict__ wn = Wnl + (cc * 2 + o) * 32;
        float acc = 0.f;
#pragma unroll
        for (int i = 0; i < 16; ++i) acc += F2[i * 20 + w] * wn[i];
#pragma unroll
        for (int i = 0; i < 16; ++i) acc += F2[i * 20 + 10 + w] * wn[16 + i];
        nls[tid] = acc;  // slot = c*20 + o*10 + w
    }
    __syncthreads();
    // out[b,c,o] = sum_w nl[w,c,o] * Wout_o[c,w]
    if (tid < 32) {
        const int cc = tid >> 1, o = tid & 1;
        const float* __restrict__ wo = (o == 0 ? Wor : Woi) + cc * WW;
        float acc = 0.f;
#pragma unroll
        for (int w = 0; w < WW; ++w) acc += nls[cc * 20 + o * 10 + w] * wo[w];
        outraw[b * 32 + cc * 2 + o] = acc;
    }
}

// ---------------- Kernel 2: BatchNorm in place on d_out ----------------
__global__ __launch_bounds__(256) void bnorm(float* __restrict__ out,
                                             const float* __restrict__ gamma,
                                             const float* __restrict__ beta) {
    const int c = blockIdx.x;   // [0,16)
    const int t = threadIdx.x;  // [0,256) == b
    const float v0 = out[t * 32 + c * 2 + 0];
    const float v1 = out[t * 32 + c * 2 + 1];
    float s = v0 + v1;
    float ss = v0 * v0 + v1 * v1;
#pragma unroll
    for (int off = 32; off > 0; off >>= 1) {
        s += __shfl_down(s, off, 64);
        ss += __shfl_down(ss, off, 64);
    }
    __shared__ float ls[8];
    const int wave = t >> 6, lane = t & 63;
    if (lane == 0) { ls[wave * 2] = s; ls[wave * 2 + 1] = ss; }
    __syncthreads();
    const float S = ls[0] + ls[2] + ls[4] + ls[6];
    const float SS = ls[1] + ls[3] + ls[5] + ls[7];
    const float mean = S * (1.f / 512.f);
    const float var = SS * (1.f / 512.f) - mean * mean;
    const float scale = gamma[c] * rsqrtf(var + EPSF);
    const float sh = beta[c];
    out[t * 32 + c * 2 + 0] = (v0 - mean) * scale + sh;
    out[t * 32 + c * 2 + 1] = (v1 - mean) * scale + sh;
}

extern "C" void kernel_launch(void* const* d_in, const int* in_sizes, int n_in,
                              void* d_out, int out_size, void* d_ws, size_t ws_size,
                              hipStream_t stream) {
    const float* x     = (const float*)d_in[0];
    const float* Wr    = (const float*)d_in[1];
    const float* Wi    = (const float*)d_in[2];
    const float* Wnl   = (const float*)d_in[3];
    const float* Wor   = (const float*)d_in[4];
    const float* Woi   = (const float*)d_in[5];
    const float* gamma = (const float*)d_in[6];
    const float* beta  = (const float*)d_in[7];
    float* out = (float*)d_out;

    const size_t pk_bytes = (size_t)NN * CC * sizeof(float2);  // 524288
    float2* pk = (float2*)d_ws;
    const bool use_pk = (ws_size >= pk_bytes);  // ws_size fixed -> same path every call

    if (use_pk) {
        hipLaunchKernelGGL(pack_weights, dim3(256), dim3(256), 0, stream, Wr, Wi, pk);
        hipLaunchKernelGGL((fused_main<true>), dim3(BB), dim3(1024), 0, stream,
                           x, pk, Wr, Wi, Wnl, Wor, Woi, out);
    } else {
        hipLaunchKernelGGL((fused_main<false>), dim3(BB), dim3(1024), 0, stream,
                           x, pk, Wr, Wi, Wnl, Wor, Woi, out);
    }
    hipLaunchKernelGGL(bnorm, dim3(CC), dim3(256), 0, stream, out, gamma, beta);
}

// Round 2
// 210.965 us; speedup vs baseline: 1.7048x; 1.7048x over previous
//
#include <hip/hip_runtime.h>

#define BB 256
#define NN 4096
#define CC 16
#define WW 10
#define LL 4087  // N - W + 1
#define EPSF 1e-5f

// ---------------- Kernel 0: pack + zero-pad weights into ws (512 KB) ----------------
// pk[n*16+c] = {Wr[c,n], Wi[c,n]}, zeros for n >= LL
__global__ __launch_bounds__(256) void pack_weights(const float* __restrict__ Wr,
                                                    const float* __restrict__ Wi,
                                                    float2* __restrict__ pk) {
    int tg = blockIdx.x * 256 + threadIdx.x;  // [0, 65536)
    int n = tg >> 4, c = tg & 15;
    float2 v = make_float2(0.f, 0.f);
    if (n < LL) { v.x = Wr[c * LL + n]; v.y = Wi[c * LL + n]; }
    pk[tg] = v;
}

// ---------------- Kernel 1: fused stage1+2+3, one block per b, 1024 threads ----------------
// 1024 threads = 64 tc (n-chunks of 64) x 16 c. x read exactly once as float2.
// NOTE (R3): float4/lane + nontemporal loads regressed (−11.6 us); keep float2, no nt.
// NOTE (R5): fusing BN via last-block finalizer regressed (−9.4 us); keep separate bnorm.
// NOTE (R6 FAILED): xb[16] batching under default __launch_bounds__(1024) -> compiler
//   capped VGPR at 64 -> scratch spills (WRITE_SIZE 319MB vs 32KB expected), 65->213us.
//   Lesson: grid=256 blocks of 1024 = 1 block/CU = 4 waves/EU ALWAYS; 64-VGPR cap buys
//   nothing. R7: __launch_bounds__(1024,4) (cap=128 VGPR), batch xb[16]+wb[16] per
//   chunk, static 9-elem weight tail instead of rotating window. ~115 regs, no spill.
template <bool PK>
__global__ __launch_bounds__(1024, 4) void fused_main(const float* __restrict__ x,
                                                      const float2* __restrict__ pk,
                                                      const float* __restrict__ Wr,
                                                      const float* __restrict__ Wi,
                                                      const float* __restrict__ Wnl,
                                                      const float* __restrict__ Wor,
                                                      const float* __restrict__ Woi,
                                                      float* __restrict__ outraw) {
    const int b = blockIdx.x;
    const int tid = threadIdx.x;
    const int tc = tid >> 4;   // 0..63
    const int c = tid & 15;
    const int n0 = tc * 64;

    const float2* __restrict__ x2 = (const float2*)x + (size_t)b * (NN * CC) + (n0 * 16 + c);
    const float2* __restrict__ pkp = pk + (n0 * 16 + c);

    // carried tail: weights n_chunkstart-9 .. n_chunkstart-1  (tr[j] = W[start-9+j])
    float tr[9], ti[9];
    float fr[WW], fi[WW];
#pragma unroll
    for (int w = 0; w < WW; ++w) { fr[w] = 0.f; fi[w] = 0.f; }

    // prefill tail with weights n0-9..n0-1 (zero if negative)
#pragma unroll
    for (int j = 0; j < 9; ++j) {
        const int m = n0 - 9 + j;
        float vr = 0.f, vi = 0.f;
        if (PK) {
            if (m >= 0) { const float2 t = pk[m * 16 + c]; vr = t.x; vi = t.y; }
        } else {
            const int mc = m < 0 ? 0 : m;
            const float a = Wr[c * LL + mc], q = Wi[c * LL + mc];
            vr = (m >= 0) ? a : 0.f;
            vi = (m >= 0) ? q : 0.f;
        }
        tr[j] = vr;
        ti[j] = vi;
    }

    // main loop: 4 chunks of 16 steps; one chunk's batch buffers live at a time.
#pragma unroll 1
    for (int g = 0; g < 4; ++g) {
        const int nb = n0 + g * 16;
        float2 xb[16], wb[16];
        // batch-issue all 32 independent loads for this chunk; FMAs below consume
        // them as they return (pipelined), 4 waves/EU hide the leading latency.
#pragma unroll
        for (int p = 0; p < 16; ++p) {
            xb[p] = x2[p * 16];
            if (PK) {
                wb[p] = pkp[p * 16];
            } else {
                const int n = nb + p;
                const int nc2 = (n < LL) ? n : (LL - 1);
                const float a = Wr[c * LL + nc2], q = Wi[c * LL + nc2];
                wb[p].x = (n < LL) ? a : 0.f;
                wb[p].y = (n < LL) ? q : 0.f;
            }
        }
        x2 += 256;   // 16 steps * 16 channels
        pkp += 256;

#pragma unroll
        for (int p = 0; p < 16; ++p) {
#pragma unroll
            for (int w = 0; w < WW; ++w) {
                const int q = p - w;  // compile-time constant
                const float wr_ = (q >= 0) ? wb[q].x : tr[q + 9];
                const float wi_ = (q >= 0) ? wb[q].y : ti[q + 9];
                fr[w] += xb[p].x * wr_;
                fi[w] += xb[p].y * wi_;
            }
        }
        // next chunk's tail = this chunk's weights at steps 7..15
#pragma unroll
        for (int j = 0; j < 9; ++j) { tr[j] = wb[j + 7].x; ti[j] = wb[j + 7].y; }
    }

    // reduce over tc: within a wave tc occupies lane bits 4..5 -> xor-reduce,
    // then 16 wave-partials via LDS.
#pragma unroll
    for (int w = 0; w < WW; ++w) {
        fr[w] += __shfl_xor(fr[w], 16);
        fr[w] += __shfl_xor(fr[w], 32);
        fi[w] += __shfl_xor(fi[w], 16);
        fi[w] += __shfl_xor(fi[w], 32);
    }
    __shared__ float red[16][320];
    __shared__ float F2[320];
    __shared__ float nls[320];
    const int lane = tid & 63, wave = tid >> 6;
    if (lane < 16) {  // lane == c for these lanes
#pragma unroll
        for (int w = 0; w < WW; ++w) {
            red[wave][lane * 20 + w] = fr[w];
            red[wave][lane * 20 + 10 + w] = fi[w];
        }
    }
    __syncthreads();
    if (tid < 320) {
        float s = 0.f;
#pragma unroll
        for (int k = 0; k < 16; ++k) s += red[k][tid];
        F2[tid] = s;  // slot = c*20 + j*10 + w  (j=0:real, 1:imag)
    }
    __syncthreads();
    // amplitude scaling
    if (tid < 160) {
        const int cc = tid / 10, w = tid % 10;
        const float a = F2[cc * 20 + w], q = F2[cc * 20 + 10 + w];
        const float amp = a * a + q * q;
        F2[cc * 20 + w] = a * amp;
        F2[cc * 20 + 10 + w] = q * amp;
    }
    __syncthreads();
    // nl[w,c,o] = sum_i tf[w,i] * Wnl[c,o,i]
    if (tid < 320) {
        const int cc = tid / 20, rem = tid % 20, o = rem / 10, w = rem % 10;
        const float* __restrict__ wn = Wnl + (cc * 2 + o) * 32;
        float acc = 0.f;
#pragma unroll
        for (int i = 0; i < 16; ++i) acc += F2[i * 20 + w] * wn[i];
#pragma unroll
        for (int i = 0; i < 16; ++i) acc += F2[i * 20 + 10 + w] * wn[16 + i];
        nls[tid] = acc;  // slot = c*20 + o*10 + w
    }
    __syncthreads();
    // out[b,c,o] = sum_w nl[w,c,o] * Wout_o[c,w]
    if (tid < 32) {
        const int cc = tid >> 1, o = tid & 1;
        const float* __restrict__ wo = (o == 0 ? Wor : Woi) + cc * WW;
        float acc = 0.f;
#pragma unroll
        for (int w = 0; w < WW; ++w) acc += nls[cc * 20 + o * 10 + w] * wo[w];
        outraw[b * 32 + cc * 2 + o] = acc;
    }
}

// ---------------- Kernel 2: BatchNorm in place on d_out ----------------
__global__ __launch_bounds__(256) void bnorm(float* __restrict__ out,
                                             const float* __restrict__ gamma,
                                             const float* __restrict__ beta) {
    const int c = blockIdx.x;   // [0,16)
    const int t = threadIdx.x;  // [0,256) == b
    const float v0 = out[t * 32 + c * 2 + 0];
    const float v1 = out[t * 32 + c * 2 + 1];
    float s = v0 + v1;
    float ss = v0 * v0 + v1 * v1;
#pragma unroll
    for (int off = 32; off > 0; off >>= 1) {
        s += __shfl_down(s, off, 64);
        ss += __shfl_down(ss, off, 64);
    }
    __shared__ float ls[8];
    const int wave = t >> 6, lane = t & 63;
    if (lane == 0) { ls[wave * 2] = s; ls[wave * 2 + 1] = ss; }
    __syncthreads();
    const float S = ls[0] + ls[2] + ls[4] + ls[6];
    const float SS = ls[1] + ls[3] + ls[5] + ls[7];
    const float mean = S * (1.f / 512.f);
    const float var = SS * (1.f / 512.f) - mean * mean;
    const float scale = gamma[c] * rsqrtf(var + EPSF);
    const float sh = beta[c];
    out[t * 32 + c * 2 + 0] = (v0 - mean) * scale + sh;
    out[t * 32 + c * 2 + 1] = (v1 - mean) * scale + sh;
}

extern "C" void kernel_launch(void* const* d_in, const int* in_sizes, int n_in,
                              void* d_out, int out_size, void* d_ws, size_t ws_size,
                              hipStream_t stream) {
    const float* x     = (const float*)d_in[0];
    const float* Wr    = (const float*)d_in[1];
    const float* Wi    = (const float*)d_in[2];
    const float* Wnl   = (const float*)d_in[3];
    const float* Wor   = (const float*)d_in[4];
    const float* Woi   = (const float*)d_in[5];
    const float* gamma = (const float*)d_in[6];
    const float* beta  = (const float*)d_in[7];
    float* out = (float*)d_out;

    const size_t pk_bytes = (size_t)NN * CC * sizeof(float2);  // 524288
    float2* pk = (float2*)d_ws;
    const bool use_pk = (ws_size >= pk_bytes);  // ws_size fixed -> same path every call

    if (use_pk) {
        hipLaunchKernelGGL(pack_weights, dim3(256), dim3(256), 0, stream, Wr, Wi, pk);
        hipLaunchKernelGGL((fused_main<true>), dim3(BB), dim3(1024), 0, stream,
                           x, pk, Wr, Wi, Wnl, Wor, Woi, out);
    } else {
        hipLaunchKernelGGL((fused_main<false>), dim3(BB), dim3(1024), 0, stream,
                           x, pk, Wr, Wi, Wnl, Wor, Woi, out);
    }
    hipLaunchKernelGGL(bnorm, dim3(CC), dim3(256), 0, stream, out, gamma, beta);
}